// Round 1
// baseline (1269.193 us; speedup 1.0000x reference)
//
#include <hip/hip_runtime.h>
#include <math.h>

// Problem dims (fixed by reference)
#define TT 10
#define BB 32
#define CIN 3
#define COUT 64
#define HH 64
#define WW 64
#define HW (HH*WW)           // 4096
#define DECAY 0.2f
#define INH 1.625f

// ---------------------------------------------------------------------------
// Conv kernel: one block = (b, 4 rows), 256 threads = 64 w x 4 h.
// Each thread computes all 64 output channels at its (b,h,w), writes i to ws,
// and participates in a per-channel block max -> atomicMax (sortable uint).
// ---------------------------------------------------------------------------
__global__ __launch_bounds__(256) void conv_kernel(
    const float* __restrict__ x,      // (B,3,64,64) for this step
    const float* __restrict__ Wt,     // (64,3,3,3)
    float* __restrict__ icur,         // (B,64,64,64)
    unsigned int* __restrict__ thr_raw) // [64] for this step, pre-zeroed
{
    __shared__ float sx[CIN][6][66];
    __shared__ float sw[COUT*27];
    __shared__ float wmax[COUT*4];

    const int tid = threadIdx.x;
    const int h0 = blockIdx.x * 4;
    const int b  = blockIdx.y;

    // load weights (1728 floats)
    for (int l = tid; l < COUT*27; l += 256) sw[l] = Wt[l];

    // load x tile: 3 x 6 x 66 (zero-padded borders)
    const float* xb = x + (size_t)b * (CIN*HW);
    for (int l = tid; l < CIN*6*66; l += 256) {
        int ci  = l / 396;
        int r   = (l % 396) / 66;
        int col = l % 66;
        int gh = h0 + r - 1;
        int gw = col - 1;
        float v = 0.f;
        if (gh >= 0 && gh < HH && gw >= 0 && gw < WW)
            v = xb[ci*HW + gh*WW + gw];
        sx[ci][r][col] = v;
    }
    __syncthreads();

    const int wt   = tid & 63;   // w within row
    const int ht   = tid >> 6;   // row within tile (0..3)
    const int lane = tid & 63;
    const int wave = tid >> 6;

    // gather the 27 input values this thread needs (shared across all c)
    float xv[27];
    #pragma unroll
    for (int ci = 0; ci < CIN; ci++)
        #pragma unroll
        for (int kh = 0; kh < 3; kh++)
            #pragma unroll
            for (int kw = 0; kw < 3; kw++)
                xv[ci*9 + kh*3 + kw] = sx[ci][ht+kh][wt+kw];

    float* ib = icur + (size_t)b*(COUT*HW) + (h0+ht)*WW + wt;

    for (int c = 0; c < COUT; c++) {
        float acc = 0.f;
        #pragma unroll
        for (int k = 0; k < 27; k++) acc = fmaf(sw[c*27+k], xv[k], acc);
        ib[(size_t)c*HW] = acc;
        // wave-level max (64 lanes)
        float m = acc;
        #pragma unroll
        for (int off = 32; off > 0; off >>= 1)
            m = fmaxf(m, __shfl_xor(m, off, 64));
        if (lane == 0) wmax[c*4 + wave] = m;
    }
    __syncthreads();

    if (tid < COUT) {
        float m = fmaxf(fmaxf(wmax[tid*4+0], wmax[tid*4+1]),
                        fmaxf(wmax[tid*4+2], wmax[tid*4+3]));
        unsigned int u = __float_as_uint(m);
        u = (u & 0x80000000u) ? ~u : (u | 0x80000000u);  // sortable encoding
        atomicMax(&thr_raw[tid], u);
    }
}

// ---------------------------------------------------------------------------
// LIF + ATB/ASF + WTA + inhibition. One thread per (b,h,w), loops 64 channels,
// mem1[64] held in registers (fully unrolled).
// ---------------------------------------------------------------------------
__global__ __launch_bounds__(256) void lif_kernel(
    const float* __restrict__ icur,        // (B,64,64,64)
    const unsigned int* __restrict__ thr_raw, // [64]
    float* __restrict__ mem,               // (B,64,64,64) persistent
    float* __restrict__ out,               // (B,64,64,64) for this step
    int first)
{
    __shared__ float sthr[COUT], sinv[COUT], s04[COUT], sinh_[COUT];
    const int tid = threadIdx.x;
    if (tid < COUT) {
        unsigned int u = thr_raw[tid];
        u = (u & 0x80000000u) ? (u & 0x7FFFFFFFu) : ~u;  // decode
        float thr = __uint_as_float(u) + 1e-4f;
        sthr[tid]  = thr;
        sinv[tid]  = 8.0f / thr;
        s04[tid]   = 0.4f * thr;
        sinh_[tid] = INH * thr;
    }
    __syncthreads();

    const int idx = blockIdx.x * 256 + tid;    // 0 .. B*HW-1
    const int b  = idx >> 12;
    const int hw = idx & (HW-1);

    const float* ib = icur + (size_t)b*(COUT*HW) + hw;
    float*       mb = mem  + (size_t)b*(COUT*HW) + hw;
    float*       ob = out  + (size_t)b*(COUT*HW) + hw;

    float m1[COUT];
    float best = -INFINITY;
    int wc = 0;
    int bestSpike = 0;

    #pragma unroll
    for (int c = 0; c < COUT; c++) {
        float iv  = ib[c*HW];
        float mp  = first ? 0.f : mb[c*HW];
        float cur = fmaxf(iv, 0.f);
        float z   = (cur - s04[c]) * sinv[c];
        float sig = 1.0f / (1.0f + expf(-z));
        float asf = sthr[c] * sig;
        float m   = mp * DECAY + asf;
        m1[c] = m;
        int   sp    = m > sthr[c];
        float score = sp ? m : 0.f;
        if (score > best) { best = score; wc = c; bestSpike = sp; }
    }

    #pragma unroll
    for (int c = 0; c < COUT; c++) {
        int   fired = (c == wc) && bestSpike;
        float outv  = fired ? 1.f : 0.f;
        float mnew  = fired ? 0.f : (m1[c] - (bestSpike ? sinh_[c] : 0.f));
        ob[c*HW] = outv;
        mb[c*HW] = mnew;
    }
}

// ---------------------------------------------------------------------------
extern "C" void kernel_launch(void* const* d_in, const int* in_sizes, int n_in,
                              void* d_out, int out_size, void* d_ws, size_t ws_size,
                              hipStream_t stream) {
    const float* x  = (const float*)d_in[0];   // (T,B,3,64,64)
    const float* W  = (const float*)d_in[1];   // (64,3,3,3)
    float* out      = (float*)d_out;           // (T,B,64,64,64)

    char* ws = (char*)d_ws;
    const size_t IBYTES = (size_t)BB*COUT*HW*sizeof(float);   // 33.5 MB
    float* ibuf         = (float*)ws;
    float* mem          = (float*)(ws + IBYTES);
    unsigned int* thr   = (unsigned int*)(ws + 2*IBYTES);     // [T][64]

    hipMemsetAsync(thr, 0, TT*COUT*sizeof(unsigned int), stream);

    for (int t = 0; t < TT; t++) {
        conv_kernel<<<dim3(HH/4, BB), 256, 0, stream>>>(
            x + (size_t)t*BB*CIN*HW, W, ibuf, thr + t*COUT);
        lif_kernel<<<(BB*HW)/256, 256, 0, stream>>>(
            ibuf, thr + t*COUT, mem, out + (size_t)t*BB*COUT*HW, t == 0);
    }
}

// Round 3
// 666.596 us; speedup vs baseline: 1.9040x; 1.9040x over previous
//
#include <hip/hip_runtime.h>
#include <math.h>

#define TT 10
#define BB 32
#define CIN 3
#define COUT 64
#define HH 64
#define WW 64
#define HW (HH*WW)           // 4096
#define DECAY 0.2f
#define INH 1.625f

// ---------------------------------------------------------------------------
// Pass 1: per-(t,c) adaptive threshold = max over (B,H,W) of conv output.
// thr[t] depends only on x[t] and W — no membrane state — so all T steps run
// in parallel. Conv values are transient (never stored).
// Grid (16 rowgroups, 32 batch, 10 t) x 256 threads (64w x 4h).
// ---------------------------------------------------------------------------
__global__ __launch_bounds__(256) void thr_kernel(
    const float* __restrict__ x,        // (T,B,3,64,64)
    const float* __restrict__ Wt,       // (64,3,3,3)
    unsigned int* __restrict__ thr_raw) // (T,64), pre-zeroed
{
    __shared__ float sx[CIN][6][66];
    __shared__ float wmax[COUT][4];

    const int tid  = threadIdx.x;
    const int wt   = tid & 63;
    const int ht   = tid >> 6;
    const int lane = tid & 63;
    const int wave = tid >> 6;
    const int h0   = blockIdx.x * 4;
    const int b    = blockIdx.y;
    const int t    = blockIdx.z;

    // stage x tile (3 x 6 x 66, zero-padded)
    const float* xb = x + ((size_t)t * BB + b) * (CIN * HW);
    for (int l = tid; l < CIN * 6 * 66; l += 256) {
        int ci  = l / 396;
        int r   = (l % 396) / 66;
        int col = l % 66;
        int gh = h0 + r - 1;
        int gw = col - 1;
        float v = 0.f;
        if (gh >= 0 && gh < HH && gw >= 0 && gw < WW)
            v = xb[ci * HW + gh * WW + gw];
        sx[ci][r][col] = v;
    }
    __syncthreads();

    float xv[27];
    #pragma unroll
    for (int ci = 0; ci < CIN; ci++)
        #pragma unroll
        for (int kh = 0; kh < 3; kh++)
            #pragma unroll
            for (int kw = 0; kw < 3; kw++)
                xv[ci * 9 + kh * 3 + kw] = sx[ci][ht + kh][wt + kw];

    #pragma unroll
    for (int c = 0; c < COUT; c++) {
        float acc = 0.f;
        #pragma unroll
        for (int k = 0; k < 27; k++)
            acc = fmaf(Wt[c * 27 + k], xv[k], acc);   // uniform -> s_load
        float m = acc;
        #pragma unroll
        for (int off = 32; off > 0; off >>= 1)
            m = fmaxf(m, __shfl_xor(m, off, 64));
        if (lane == 0) wmax[c][wave] = m;
    }
    __syncthreads();

    if (tid < COUT) {
        float m = fmaxf(fmaxf(wmax[tid][0], wmax[tid][1]),
                        fmaxf(wmax[tid][2], wmax[tid][3]));
        unsigned int u = __float_as_uint(m);
        u = (u & 0x80000000u) ? ~u : (u | 0x80000000u);  // sortable encode
        atomicMax(&thr_raw[t * COUT + tid], u);
    }
}

// ---------------------------------------------------------------------------
// Pass 2: full sequential T-loop. One thread per (b,h,w); mem[64] lives in
// registers across all timesteps. Conv is recomputed per step (cheaper than
// round-tripping i through HBM) and fused directly into the LIF update so no
// iv[64] array is needed. thr comes precomputed from pass 1 — no global sync.
// Grid 512 blocks (32 b x 16 rowgroups) x 256 threads.
// ---------------------------------------------------------------------------
__global__ __launch_bounds__(256) void lif_kernel(
    const float* __restrict__ x,            // (T,B,3,64,64)
    const float* __restrict__ Wt,           // (64,3,3,3)
    const unsigned int* __restrict__ thr_raw, // (T,64)
    float* __restrict__ out)                // (T,B,64,64,64)
{
    __shared__ float sx[CIN][6][66];
    __shared__ float sthr[COUT], sinv[COUT], s04[COUT], sinh_[COUT];

    const int tid = threadIdx.x;
    const int wt  = tid & 63;
    const int ht  = tid >> 6;
    const int b   = blockIdx.x >> 4;
    const int h0  = (blockIdx.x & 15) * 4;

    float mem[COUT];
    #pragma unroll
    for (int c = 0; c < COUT; c++) mem[c] = 0.f;

    for (int t = 0; t < TT; t++) {
        __syncthreads();   // all reads of sx/sthr from previous step done

        // stage x tile + decode this step's thresholds
        const float* xb = x + ((size_t)t * BB + b) * (CIN * HW);
        for (int l = tid; l < CIN * 6 * 66; l += 256) {
            int ci  = l / 396;
            int r   = (l % 396) / 66;
            int col = l % 66;
            int gh = h0 + r - 1;
            int gw = col - 1;
            float v = 0.f;
            if (gh >= 0 && gh < HH && gw >= 0 && gw < WW)
                v = xb[ci * HW + gh * WW + gw];
            sx[ci][r][col] = v;
        }
        if (tid < COUT) {
            unsigned int u = thr_raw[t * COUT + tid];
            u = (u & 0x80000000u) ? (u & 0x7FFFFFFFu) : ~u;  // decode
            float thr = __uint_as_float(u) + 1e-4f;
            sthr[tid]  = thr;
            sinv[tid]  = 8.0f / thr;
            s04[tid]   = 0.4f * thr;
            sinh_[tid] = INH * thr;
        }
        __syncthreads();

        float xv[27];
        #pragma unroll
        for (int ci = 0; ci < CIN; ci++)
            #pragma unroll
            for (int kh = 0; kh < 3; kh++)
                #pragma unroll
                for (int kw = 0; kw < 3; kw++)
                    xv[ci * 9 + kh * 3 + kw] = sx[ci][ht + kh][wt + kw];

        // conv fused with ASF/LIF per channel; WTA argmax tracked on the fly
        float best = -INFINITY;
        int wc = 0, sp = 0;
        #pragma unroll
        for (int c = 0; c < COUT; c++) {
            float acc = 0.f;
            #pragma unroll
            for (int k = 0; k < 27; k++)
                acc = fmaf(Wt[c * 27 + k], xv[k], acc);   // uniform -> s_load
            float cur = fmaxf(acc, 0.f);
            float z   = (cur - s04[c]) * sinv[c];
            float sig = 1.0f / (1.0f + expf(-z));
            float m   = mem[c] * DECAY + sthr[c] * sig;
            mem[c] = m;
            int   s     = m > sthr[c];
            float score = s ? m : 0.f;
            if (score > best) { best = score; wc = c; sp = s; }
        }

        float* ob = out + (((size_t)t * BB + b) * COUT) * HW + (h0 + ht) * WW + wt;
        #pragma unroll
        for (int c = 0; c < COUT; c++) {
            int fired = (c == wc) && sp;
            ob[(size_t)c * HW] = fired ? 1.f : 0.f;
            mem[c] = fired ? 0.f : (mem[c] - (sp ? sinh_[c] : 0.f));
        }
    }
}

// ---------------------------------------------------------------------------
extern "C" void kernel_launch(void* const* d_in, const int* in_sizes, int n_in,
                              void* d_out, int out_size, void* d_ws, size_t ws_size,
                              hipStream_t stream) {
    const float* x = (const float*)d_in[0];   // (T,B,3,64,64)
    const float* W = (const float*)d_in[1];   // (64,3,3,3)
    float* out     = (float*)d_out;           // (T,B,64,64,64)

    unsigned int* thr = (unsigned int*)d_ws;  // (T,64)
    hipMemsetAsync(thr, 0, TT * COUT * sizeof(unsigned int), stream);

    thr_kernel<<<dim3(HH/4, BB, TT), 256, 0, stream>>>(x, W, thr);
    lif_kernel<<<dim3((BB * HW) / (64 * 4)), 256, 0, stream>>>(x, W, thr, out);
}